// Round 11
// baseline (316.031 us; speedup 1.0000x reference)
//
#include <hip/hip_runtime.h>
#include <hip/hip_bf16.h>

#define N_NODES 50000
#define N_EDGES 800000
#define IN_F    128
#define HID     16
#define HEADS   8
#define F1      128   // HEADS*HID
#define CLS     40
#define CLSP    64    // padded bf16 feat2 stride
#define NEG     0.2f
#define NEG_INF (-__builtin_inff())
#define SWEEPS      8
#define SWEEP_RANGE 6250   // N_NODES / SWEEPS (scatter)
#define STRIDE      96     // padded CSR slot count per node
#define GSWEEPS     4
#define GWIN        12500  // src-window for gather sweeps (3.2MB feat1b / 1.6MB feat2p)

typedef __bf16 bf16x8 __attribute__((ext_vector_type(8)));
typedef float  f32x4  __attribute__((ext_vector_type(4)));
typedef float  f32x2  __attribute__((ext_vector_type(2)));

__device__ __forceinline__ float leaky(float v) { return v >= 0.0f ? v : NEG * v; }
__device__ __forceinline__ f32x2 unpk(unsigned u) {
    f32x2 r;
    r.x = __uint_as_float(u << 16);
    r.y = __uint_as_float(u & 0xffff0000u);
    return r;
}

// ---------------- setup: zero cursor + weight transposes ----------------
__global__ void setup_kernel(const float* __restrict__ W1, const float* __restrict__ W2,
                             __bf16* __restrict__ w1t, __bf16* __restrict__ w2t,
                             int* __restrict__ cursor) {
    int i = blockIdx.x * blockDim.x + threadIdx.x;
    if (i < N_NODES) cursor[i] = 0;
    if (i < 128 * 128) {
        int n = i >> 7, k = i & 127;
        w1t[i] = (__bf16)W1[k * 128 + n];
    }
    if (i < CLSP * 128) {
        int n = i >> 7, k = i & 127;
        w2t[i] = (n < CLS) ? (__bf16)W2[k * CLS + n] : (__bf16)0.0f;
    }
}

// ---------------- swept scatter into padded CSR ----------------
__global__ void scatter_kernel(const int* __restrict__ src, const int* __restrict__ dst,
                               int* __restrict__ cursor, int* __restrict__ srcs_sorted) {
    const int BPS = (N_EDGES + 255) / 256;
    int sweep = blockIdx.x / BPS;
    int e = (blockIdx.x - sweep * BPS) * 256 + threadIdx.x;
    if (e >= N_EDGES) return;
    int d = dst[e];
    int lo = sweep * SWEEP_RANGE;
    if (d < lo || d >= lo + SWEEP_RANGE) return;
    int pos = d * STRIDE + atomicAdd(&cursor[d], 1);
    srcs_sorted[pos] = src[e];
}

// ---------------- GEMM1 + fused elr1 epilogue ----------------
__global__ __launch_bounds__(256) void gemm1_mfma(const float* __restrict__ A,
                                                  const __bf16* __restrict__ Wt,
                                                  const float* __restrict__ al1,
                                                  const float* __restrict__ ar1,
                                                  __bf16* __restrict__ outb,
                                                  float* __restrict__ el,
                                                  float* __restrict__ er) {
    int wave = threadIdx.x >> 6, lane = threadIdx.x & 63;
    int m0 = blockIdx.x * 64 + wave * 16;
    int c = lane & 15;
    int row = m0 + c;
    int rowc = row < N_NODES ? row : N_NODES - 1;
    int ko = (lane >> 4) * 8;

    f32x4 acc[8];
    #pragma unroll
    for (int t = 0; t < 8; ++t)
        #pragma unroll
        for (int r = 0; r < 4; ++r) acc[t][r] = 0.f;

    for (int ks = 0; ks < 128; ks += 32) {
        const float* ap = A + (size_t)rowc * 128 + ks + ko;
        float4 u = *(const float4*)ap;
        float4 v = *(const float4*)(ap + 4);
        bf16x8 a;
        a[0] = (__bf16)u.x; a[1] = (__bf16)u.y; a[2] = (__bf16)u.z; a[3] = (__bf16)u.w;
        a[4] = (__bf16)v.x; a[5] = (__bf16)v.y; a[6] = (__bf16)v.z; a[7] = (__bf16)v.w;
        #pragma unroll
        for (int t = 0; t < 8; ++t) {
            bf16x8 b = *(const bf16x8*)(Wt + (size_t)(t * 16 + c) * 128 + ks + ko);
            acc[t] = __builtin_amdgcn_mfma_f32_16x16x32_bf16(a, b, acc[t], 0, 0, 0);
        }
    }
    int rbase = m0 + (lane >> 4) * 4;
    #pragma unroll
    for (int t = 0; t < 8; ++t) {
        int gcol = t * 16 + c;
        #pragma unroll
        for (int r = 0; r < 4; ++r) {
            int grow = rbase + r;
            if (grow < N_NODES) outb[(size_t)grow * 128 + gcol] = (__bf16)acc[t][r];
        }
    }
    // fused elr1
    #pragma unroll
    for (int t = 0; t < 8; ++t) {
        float alv = al1[t * 16 + c];
        float arv = ar1[t * 16 + c];
        float pe[4], pr[4];
        #pragma unroll
        for (int r = 0; r < 4; ++r) { pe[r] = acc[t][r] * alv; pr[r] = acc[t][r] * arv; }
        #pragma unroll
        for (int mask = 1; mask <= 8; mask <<= 1) {
            #pragma unroll
            for (int r = 0; r < 4; ++r) {
                pe[r] += __shfl_xor(pe[r], mask, 64);
                pr[r] += __shfl_xor(pr[r], mask, 64);
            }
        }
        if (c == 0) {
            #pragma unroll
            for (int r = 0; r < 4; ++r) {
                int grow = rbase + r;
                if (grow < N_NODES) {
                    el[grow * 8 + t] = pe[r];
                    er[grow * 8 + t] = pr[r];
                }
            }
        }
    }
}

// ---------------- GEMM2 + fused elr2 epilogue ----------------
__global__ __launch_bounds__(256) void gemm2_mfma(const __bf16* __restrict__ A,
                                                  const __bf16* __restrict__ Wt,
                                                  const float* __restrict__ al2,
                                                  const float* __restrict__ ar2,
                                                  __bf16* __restrict__ out,
                                                  float* __restrict__ el,
                                                  float* __restrict__ er) {
    int wave = threadIdx.x >> 6, lane = threadIdx.x & 63;
    int m0 = blockIdx.x * 64 + wave * 16;
    int c = lane & 15;
    int row = m0 + c;
    int rowc = row < N_NODES ? row : N_NODES - 1;
    int ko = (lane >> 4) * 8;

    f32x4 acc[4];
    #pragma unroll
    for (int t = 0; t < 4; ++t)
        #pragma unroll
        for (int r = 0; r < 4; ++r) acc[t][r] = 0.f;

    for (int ks = 0; ks < 128; ks += 32) {
        bf16x8 a = *(const bf16x8*)(A + (size_t)rowc * 128 + ks + ko);
        #pragma unroll
        for (int t = 0; t < 4; ++t) {
            bf16x8 b = *(const bf16x8*)(Wt + (size_t)(t * 16 + c) * 128 + ks + ko);
            acc[t] = __builtin_amdgcn_mfma_f32_16x16x32_bf16(a, b, acc[t], 0, 0, 0);
        }
    }
    int rbase = m0 + (lane >> 4) * 4;
    #pragma unroll
    for (int t = 0; t < 4; ++t) {
        int gcol = t * 16 + c;
        #pragma unroll
        for (int r = 0; r < 4; ++r) {
            int grow = rbase + r;
            if (grow < N_NODES) out[(size_t)grow * CLSP + gcol] = (__bf16)acc[t][r];
        }
    }
    float pe[4] = {0.f, 0.f, 0.f, 0.f}, pr[4] = {0.f, 0.f, 0.f, 0.f};
    #pragma unroll
    for (int t = 0; t < 3; ++t) {
        int idx = t * 16 + c;
        float alv = (idx < CLS) ? al2[idx] : 0.f;
        float arv = (idx < CLS) ? ar2[idx] : 0.f;
        #pragma unroll
        for (int r = 0; r < 4; ++r) { pe[r] += acc[t][r] * alv; pr[r] += acc[t][r] * arv; }
    }
    #pragma unroll
    for (int mask = 1; mask <= 8; mask <<= 1) {
        #pragma unroll
        for (int r = 0; r < 4; ++r) {
            pe[r] += __shfl_xor(pe[r], mask, 64);
            pr[r] += __shfl_xor(pr[r], mask, 64);
        }
    }
    if (c == 0) {
        #pragma unroll
        for (int r = 0; r < 4; ++r) {
            int grow = rbase + r;
            if (grow < N_NODES) { el[grow] = pe[r]; er[grow] = pr[r]; }
        }
    }
}

// ---------------- fused GAT layer 1 (src-window swept gather) ----------------
__global__ __launch_bounds__(256) void gat1_fused(const int* __restrict__ degs,
                                                  const int* __restrict__ srcs,
                                                  const float* __restrict__ el,
                                                  const float* __restrict__ er,
                                                  const __bf16* __restrict__ feat1b,
                                                  const float* __restrict__ b1,
                                                  __bf16* __restrict__ hbufb) {
    __shared__ float a_lds[4][32 * 8];   // [wave][edge*8 + head], deg<=32
    __shared__ int   s_lds[4][32];
    int wave = threadIdx.x >> 6;
    int lane = threadIdx.x & 63;
    int d = blockIdx.x * 4 + wave;
    int off = d * STRIDE;
    int deg = degs[d];

    int h = lane & 7, slot = lane >> 3;
    int q = lane >> 4, fg = lane & 15, hd = fg >> 1;
    float er_d = er[d * 8 + h];

    f32x2 accv[4];
    #pragma unroll
    for (int j = 0; j < 4; ++j) { accv[j].x = 0.f; accv[j].y = 0.f; }

    bool fast = (deg <= 32);
    if (fast) {
        float sc[4];
        int sreg[4];
        float m = NEG_INF;
        #pragma unroll
        for (int it = 0; it < 4; ++it) {
            float v = NEG_INF;
            int e = it * 8 + slot;
            if (e < deg) {
                sreg[it] = srcs[off + e];
                v = leaky(el[sreg[it] * 8 + h] + er_d);
            }
            sc[it] = v;
            m = fmaxf(m, v);
        }
        float l = 0.f;
        #pragma unroll
        for (int it = 0; it < 4; ++it)
            l += (sc[it] == NEG_INF) ? 0.f : __expf(sc[it] - m);
        #pragma unroll
        for (int mask = 8; mask <= 32; mask <<= 1) {
            float m2 = __shfl_xor(m, mask, 64);
            float l2 = __shfl_xor(l, mask, 64);
            float mn = fmaxf(m, m2);
            float f1 = (m  == NEG_INF) ? 0.f : __expf(m - mn);
            float f2 = (m2 == NEG_INF) ? 0.f : __expf(m2 - mn);
            l = l * f1 + l2 * f2;
            m = mn;
        }
        float inv_l = 1.f / (l + 1e-9f);
        #pragma unroll
        for (int it = 0; it < 4; ++it) {
            int e = it * 8 + slot;
            if (e < deg) {
                a_lds[wave][e * 8 + h] = __expf(sc[it] - m) * inv_l;
                if (h == 0) s_lds[wave][e] = sreg[it];
            }
        }
    }
    __syncthreads();

    if (fast) {
        // preload this lane's (src, alpha) pairs into registers
        int   se[8];
        float av[8];
        #pragma unroll
        for (int g = 0; g < 8; ++g) {
            int k = g * 4 + q;
            if (k < deg) {
                se[g] = s_lds[wave][k];
                av[g] = a_lds[wave][k * 8 + hd];
            } else {
                se[g] = -1;   // fails every window test
                av[g] = 0.f;
            }
        }
        // swept gather: sweep s covers src in [s*GWIN,(s+1)*GWIN)
        #pragma unroll
        for (int s = 0; s < GSWEEPS; ++s) {
            int lo = s * GWIN;
            #pragma unroll
            for (int g = 0; g < 8; ++g) {
                if (se[g] >= lo && se[g] < lo + GWIN) {
                    uint4 p = *(const uint4*)(feat1b + (size_t)se[g] * F1 + fg * 8);
                    f32x2 a2; a2.x = av[g]; a2.y = av[g];
                    accv[0] += a2 * unpk(p.x);
                    accv[1] += a2 * unpk(p.y);
                    accv[2] += a2 * unpk(p.z);
                    accv[3] += a2 * unpk(p.w);
                }
            }
        }
    } else {
        // slow path (deg > 32): recompute + shuffle broadcast
        float m = NEG_INF, l = 0.f;
        for (int base = 0; base < deg; base += 8) {
            int e = base + slot;
            float v = NEG_INF;
            if (e < deg) {
                int s = srcs[off + e];
                v = leaky(el[s * 8 + h] + er_d);
            }
            float mn = fmaxf(m, v);
            float f1 = (m == NEG_INF) ? 0.f : __expf(m - mn);
            float f2 = (v == NEG_INF) ? 0.f : __expf(v - mn);
            l = l * f1 + f2;
            m = mn;
        }
        #pragma unroll
        for (int mask = 8; mask <= 32; mask <<= 1) {
            float m2 = __shfl_xor(m, mask, 64);
            float l2 = __shfl_xor(l, mask, 64);
            float mn = fmaxf(m, m2);
            float f1 = (m  == NEG_INF) ? 0.f : __expf(m - mn);
            float f2 = (m2 == NEG_INF) ? 0.f : __expf(m2 - mn);
            l = l * f1 + l2 * f2;
            m = mn;
        }
        float inv_l = 1.f / (l + 1e-9f);

        for (int base = 0; base < deg; base += 8) {
            int e = base + slot;
            float alpha = 0.f;
            int s = 0;
            if (e < deg) {
                s = srcs[off + e];
                float v = leaky(el[s * 8 + h] + er_d);
                alpha = __expf(v - m) * inv_l;
            }
            #pragma unroll
            for (int sub = 0; sub < 2; ++sub) {
                int k = sub * 4 + q;
                float a  = __shfl(alpha, k * 8 + hd, 64);
                int   ss = __shfl(s,     k * 8,      64);
                uint4 pp = *(const uint4*)(feat1b + (size_t)ss * F1 + fg * 8);
                f32x2 a2; a2.x = a; a2.y = a;
                accv[0] += a2 * unpk(pp.x);
                accv[1] += a2 * unpk(pp.y);
                accv[2] += a2 * unpk(pp.z);
                accv[3] += a2 * unpk(pp.w);
            }
        }
    }

    float acc[8];
    #pragma unroll
    for (int j = 0; j < 4; ++j) { acc[2 * j] = accv[j].x; acc[2 * j + 1] = accv[j].y; }
    #pragma unroll
    for (int i = 0; i < 8; ++i) {
        acc[i] += __shfl_xor(acc[i], 16, 64);
        acc[i] += __shfl_xor(acc[i], 32, 64);
    }
    if (q == 0) {
        bf16x8 o;
        #pragma unroll
        for (int i = 0; i < 8; ++i) {
            float v = acc[i] + b1[fg * 8 + i];
            v = v > 0.f ? v : expm1f(v);
            o[i] = (__bf16)v;
        }
        *(bf16x8*)(hbufb + (size_t)d * F1 + fg * 8) = o;
    }
}

// ---------------- fused GAT layer 2 (src-window swept gather) ----------------
__global__ __launch_bounds__(256) void gat2_fused(const int* __restrict__ degs,
                                                  const int* __restrict__ srcs,
                                                  const float* __restrict__ el,
                                                  const float* __restrict__ er,
                                                  const __bf16* __restrict__ feat2p,
                                                  const float* __restrict__ b2,
                                                  float* __restrict__ out) {
    __shared__ float a_lds[4][32];
    __shared__ int   s_lds[4][32];
    int wave = threadIdx.x >> 6;
    int lane = threadIdx.x & 63;
    int d = blockIdx.x * 4 + wave;
    int off = d * STRIDE;
    int deg = degs[d];

    float er_d = er[d];
    int q  = lane >> 4;
    int cg = lane & 15;
    f32x2 accv[2];
    accv[0].x = 0.f; accv[0].y = 0.f; accv[1].x = 0.f; accv[1].y = 0.f;

    bool fast = (deg <= 32);
    if (fast) {
        float sc = NEG_INF;
        int s0 = 0;
        if (lane < deg) {
            s0 = srcs[off + lane];
            sc = leaky(el[s0] + er_d);
        }
        float m = sc, l = (sc == NEG_INF) ? 0.f : 1.f;
        #pragma unroll
        for (int mask = 1; mask <= 32; mask <<= 1) {
            float m2 = __shfl_xor(m, mask, 64);
            float l2 = __shfl_xor(l, mask, 64);
            float mn = fmaxf(m, m2);
            float f1 = (m  == NEG_INF) ? 0.f : __expf(m - mn);
            float f2 = (m2 == NEG_INF) ? 0.f : __expf(m2 - mn);
            l = l * f1 + l2 * f2;
            m = mn;
        }
        float inv_l = 1.f / (l + 1e-9f);
        if (lane < deg) {
            a_lds[wave][lane] = __expf(sc - m) * inv_l;
            s_lds[wave][lane] = s0;
        }
    }
    __syncthreads();

    if (fast) {
        int   se[8];
        float av[8];
        #pragma unroll
        for (int g = 0; g < 8; ++g) {
            int k = g * 4 + q;
            if (k < deg) {
                se[g] = s_lds[wave][k];
                av[g] = a_lds[wave][k];
            } else {
                se[g] = -1;
                av[g] = 0.f;
            }
        }
        #pragma unroll
        for (int s = 0; s < GSWEEPS; ++s) {
            int lo = s * GWIN;
            #pragma unroll
            for (int g = 0; g < 8; ++g) {
                if (se[g] >= lo && se[g] < lo + GWIN) {
                    uint2 p = *(const uint2*)(feat2p + (size_t)se[g] * CLSP + cg * 4);
                    f32x2 a2; a2.x = av[g]; a2.y = av[g];
                    accv[0] += a2 * unpk(p.x);
                    accv[1] += a2 * unpk(p.y);
                }
            }
        }
    } else {
        float m = NEG_INF, l = 0.f;
        for (int base = 0; base < deg; base += 64) {
            int e = base + lane;
            float sc = NEG_INF;
            if (e < deg) {
                int s = srcs[off + e];
                sc = leaky(el[s] + er_d);
            }
            float mn = fmaxf(m, sc);
            float f1 = (m  == NEG_INF) ? 0.f : __expf(m - mn);
            float f2 = (sc == NEG_INF) ? 0.f : __expf(sc - mn);
            l = l * f1 + f2;
            m = mn;
        }
        #pragma unroll
        for (int mask = 1; mask <= 32; mask <<= 1) {
            float m2 = __shfl_xor(m, mask, 64);
            float l2 = __shfl_xor(l, mask, 64);
            float mn = fmaxf(m, m2);
            float f1 = (m  == NEG_INF) ? 0.f : __expf(m - mn);
            float f2 = (m2 == NEG_INF) ? 0.f : __expf(m2 - mn);
            l = l * f1 + l2 * f2;
            m = mn;
        }
        float inv_l = 1.f / (l + 1e-9f);

        for (int base = 0; base < deg; base += 64) {
            int e = base + lane;
            float alpha = 0.f;
            int s = 0;
            if (e < deg) {
                s = srcs[off + e];
                float sc = leaky(el[s] + er_d);
                alpha = __expf(sc - m) * inv_l;
            }
            int kmax = min(64, deg - base);
            int nsub = (kmax + 3) >> 2;
            for (int sub = 0; sub < nsub; ++sub) {
                int k = sub * 4 + q;
                float a  = __shfl(alpha, k, 64);
                int   ss = __shfl(s,     k, 64);
                uint2 pp = *(const uint2*)(feat2p + (size_t)ss * CLSP + cg * 4);
                f32x2 a2; a2.x = a; a2.y = a;
                accv[0] += a2 * unpk(pp.x);
                accv[1] += a2 * unpk(pp.y);
            }
        }
    }

    float acc[4];
    acc[0] = accv[0].x; acc[1] = accv[0].y; acc[2] = accv[1].x; acc[3] = accv[1].y;
    #pragma unroll
    for (int i = 0; i < 4; ++i) {
        acc[i] += __shfl_xor(acc[i], 16, 64);
        acc[i] += __shfl_xor(acc[i], 32, 64);
    }
    if (lane < 10) {   // q==0, cg<10
        float4 o;
        o.x = acc[0] + b2[cg * 4 + 0];
        o.y = acc[1] + b2[cg * 4 + 1];
        o.z = acc[2] + b2[cg * 4 + 2];
        o.w = acc[3] + b2[cg * 4 + 3];
        *(float4*)(out + (size_t)d * CLS + cg * 4) = o;
    }
}

// ---------------- launch ----------------
extern "C" void kernel_launch(void* const* d_in, const int* in_sizes, int n_in,
                              void* d_out, int out_size, void* d_ws, size_t ws_size,
                              hipStream_t stream) {
    const float* features = (const float*)d_in[0];
    const int*   esrc     = (const int*)d_in[1];
    const int*   edst     = (const int*)d_in[2];
    const float* W1       = (const float*)d_in[3];
    const float* al1      = (const float*)d_in[4];
    const float* ar1      = (const float*)d_in[5];
    const float* b1       = (const float*)d_in[6];
    const float* W2       = (const float*)d_in[7];
    const float* al2      = (const float*)d_in[8];
    const float* ar2      = (const float*)d_in[9];
    const float* b2       = (const float*)d_in[10];
    float* out = (float*)d_out;

    float* ws = (float*)d_ws;
    float*  el1    = ws;                        // 400,000
    float*  er1    = ws + 400000;               // 400,000
    float*  el2    = ws + 800000;               // 50,000
    float*  er2    = ws + 850000;               // 50,000
    int*    cursor = (int*)(ws + 900000);       // 50,000
    int*    srcs   = (int*)(ws + 950000);       // 4,800,000 (padded CSR)
    __bf16* feat1b = (__bf16*)(ws + 5750000);   // 6,400,000 bf16 (3.2M floats)
    __bf16* hbufb  = (__bf16*)(ws + 8950000);   // 6,400,000 bf16
    __bf16* feat2p = (__bf16*)(ws + 12150000);  // 3,200,000 bf16 (1.6M floats)
    __bf16* w1t    = (__bf16*)(ws + 13750000);  // 16,384 bf16
    __bf16* w2t    = (__bf16*)(ws + 13760000);  // 8,192 bf16
    // total ~13.77M floats = 55 MB

    const int B = 256;
    const int BPS = (N_EDGES + 255) / 256;

    setup_kernel<<<(N_NODES + B - 1) / B, B, 0, stream>>>(W1, W2, w1t, w2t, cursor);
    scatter_kernel<<<SWEEPS * BPS, B, 0, stream>>>(esrc, edst, cursor, srcs);

    gemm1_mfma<<<(N_NODES + 63) / 64, 256, 0, stream>>>(features, w1t, al1, ar1,
                                                        feat1b, el1, er1);
    gat1_fused<<<N_NODES / 4, B, 0, stream>>>(cursor, srcs, el1, er1, feat1b, b1, hbufb);

    gemm2_mfma<<<(N_NODES + 63) / 64, 256, 0, stream>>>(hbufb, w2t, al2, ar2,
                                                        feat2p, el2, er2);
    gat2_fused<<<N_NODES / 4, B, 0, stream>>>(cursor, srcs, el2, er2, feat2p, b2, out);
}

// Round 12
// 272.440 us; speedup vs baseline: 1.1600x; 1.1600x over previous
//
#include <hip/hip_runtime.h>
#include <hip/hip_bf16.h>

#define N_NODES 50000
#define N_EDGES 800000
#define IN_F    128
#define HID     16
#define HEADS   8
#define F1      128   // HEADS*HID
#define CLS     40
#define CLSP    64    // padded bf16 feat2 stride
#define NEG     0.2f
#define NEG_INF (-__builtin_inff())
#define SWEEPS      6
#define SWEEP_RANGE 8334   // ceil(N_NODES/SWEEPS); window = 8334*96*4B = 3.2MB (L2-resident)
#define STRIDE      96     // padded CSR slot count per node (P(deg>96) ~ 0)

typedef __bf16 bf16x8 __attribute__((ext_vector_type(8)));
typedef float  f32x4  __attribute__((ext_vector_type(4)));
typedef float  f32x2  __attribute__((ext_vector_type(2)));

__device__ __forceinline__ float leaky(float v) { return v >= 0.0f ? v : NEG * v; }
__device__ __forceinline__ f32x2 unpk(unsigned u) {
    f32x2 r;
    r.x = __uint_as_float(u << 16);
    r.y = __uint_as_float(u & 0xffff0000u);
    return r;
}

// ---------------- setup: zero cursor + weight transposes ----------------
__global__ void setup_kernel(const float* __restrict__ W1, const float* __restrict__ W2,
                             __bf16* __restrict__ w1t, __bf16* __restrict__ w2t,
                             int* __restrict__ cursor) {
    int i = blockIdx.x * blockDim.x + threadIdx.x;
    if (i < N_NODES) cursor[i] = 0;
    if (i < 128 * 128) {
        int n = i >> 7, k = i & 127;
        w1t[i] = (__bf16)W1[k * 128 + n];
    }
    if (i < CLSP * 128) {
        int n = i >> 7, k = i & 127;
        w2t[i] = (n < CLS) ? (__bf16)W2[k * CLS + n] : (__bf16)0.0f;
    }
}

// ---------------- swept scatter into padded CSR ----------------
// Sweep s handles dst in [s*8334,(s+1)*8334): writes land in a 3.2MB window.
__global__ void scatter_kernel(const int* __restrict__ src, const int* __restrict__ dst,
                               int* __restrict__ cursor, int* __restrict__ srcs_sorted) {
    const int BPS = (N_EDGES + 255) / 256;
    int sweep = blockIdx.x / BPS;
    int e = (blockIdx.x - sweep * BPS) * 256 + threadIdx.x;
    if (e >= N_EDGES) return;
    int d = dst[e];
    int lo = sweep * SWEEP_RANGE;
    if (d < lo || d >= lo + SWEEP_RANGE) return;
    int pos = d * STRIDE + atomicAdd(&cursor[d], 1);
    srcs_sorted[pos] = src[e];
}

// ---------------- GEMM1 + fused elr1 epilogue ----------------
__global__ __launch_bounds__(256) void gemm1_mfma(const float* __restrict__ A,
                                                  const __bf16* __restrict__ Wt,
                                                  const float* __restrict__ al1,
                                                  const float* __restrict__ ar1,
                                                  __bf16* __restrict__ outb,
                                                  float* __restrict__ el,
                                                  float* __restrict__ er) {
    int wave = threadIdx.x >> 6, lane = threadIdx.x & 63;
    int m0 = blockIdx.x * 64 + wave * 16;
    int c = lane & 15;
    int row = m0 + c;
    int rowc = row < N_NODES ? row : N_NODES - 1;
    int ko = (lane >> 4) * 8;

    f32x4 acc[8];
    #pragma unroll
    for (int t = 0; t < 8; ++t)
        #pragma unroll
        for (int r = 0; r < 4; ++r) acc[t][r] = 0.f;

    for (int ks = 0; ks < 128; ks += 32) {
        const float* ap = A + (size_t)rowc * 128 + ks + ko;
        float4 u = *(const float4*)ap;
        float4 v = *(const float4*)(ap + 4);
        bf16x8 a;
        a[0] = (__bf16)u.x; a[1] = (__bf16)u.y; a[2] = (__bf16)u.z; a[3] = (__bf16)u.w;
        a[4] = (__bf16)v.x; a[5] = (__bf16)v.y; a[6] = (__bf16)v.z; a[7] = (__bf16)v.w;
        #pragma unroll
        for (int t = 0; t < 8; ++t) {
            bf16x8 b = *(const bf16x8*)(Wt + (size_t)(t * 16 + c) * 128 + ks + ko);
            acc[t] = __builtin_amdgcn_mfma_f32_16x16x32_bf16(a, b, acc[t], 0, 0, 0);
        }
    }
    int rbase = m0 + (lane >> 4) * 4;
    #pragma unroll
    for (int t = 0; t < 8; ++t) {
        int gcol = t * 16 + c;
        #pragma unroll
        for (int r = 0; r < 4; ++r) {
            int grow = rbase + r;
            if (grow < N_NODES) outb[(size_t)grow * 128 + gcol] = (__bf16)acc[t][r];
        }
    }
    // fused elr1
    #pragma unroll
    for (int t = 0; t < 8; ++t) {
        float alv = al1[t * 16 + c];
        float arv = ar1[t * 16 + c];
        float pe[4], pr[4];
        #pragma unroll
        for (int r = 0; r < 4; ++r) { pe[r] = acc[t][r] * alv; pr[r] = acc[t][r] * arv; }
        #pragma unroll
        for (int mask = 1; mask <= 8; mask <<= 1) {
            #pragma unroll
            for (int r = 0; r < 4; ++r) {
                pe[r] += __shfl_xor(pe[r], mask, 64);
                pr[r] += __shfl_xor(pr[r], mask, 64);
            }
        }
        if (c == 0) {
            #pragma unroll
            for (int r = 0; r < 4; ++r) {
                int grow = rbase + r;
                if (grow < N_NODES) {
                    el[grow * 8 + t] = pe[r];
                    er[grow * 8 + t] = pr[r];
                }
            }
        }
    }
}

// ---------------- GEMM2 + fused elr2 epilogue ----------------
__global__ __launch_bounds__(256) void gemm2_mfma(const __bf16* __restrict__ A,
                                                  const __bf16* __restrict__ Wt,
                                                  const float* __restrict__ al2,
                                                  const float* __restrict__ ar2,
                                                  __bf16* __restrict__ out,
                                                  float* __restrict__ el,
                                                  float* __restrict__ er) {
    int wave = threadIdx.x >> 6, lane = threadIdx.x & 63;
    int m0 = blockIdx.x * 64 + wave * 16;
    int c = lane & 15;
    int row = m0 + c;
    int rowc = row < N_NODES ? row : N_NODES - 1;
    int ko = (lane >> 4) * 8;

    f32x4 acc[4];
    #pragma unroll
    for (int t = 0; t < 4; ++t)
        #pragma unroll
        for (int r = 0; r < 4; ++r) acc[t][r] = 0.f;

    for (int ks = 0; ks < 128; ks += 32) {
        bf16x8 a = *(const bf16x8*)(A + (size_t)rowc * 128 + ks + ko);
        #pragma unroll
        for (int t = 0; t < 4; ++t) {
            bf16x8 b = *(const bf16x8*)(Wt + (size_t)(t * 16 + c) * 128 + ks + ko);
            acc[t] = __builtin_amdgcn_mfma_f32_16x16x32_bf16(a, b, acc[t], 0, 0, 0);
        }
    }
    int rbase = m0 + (lane >> 4) * 4;
    #pragma unroll
    for (int t = 0; t < 4; ++t) {
        int gcol = t * 16 + c;
        #pragma unroll
        for (int r = 0; r < 4; ++r) {
            int grow = rbase + r;
            if (grow < N_NODES) out[(size_t)grow * CLSP + gcol] = (__bf16)acc[t][r];
        }
    }
    float pe[4] = {0.f, 0.f, 0.f, 0.f}, pr[4] = {0.f, 0.f, 0.f, 0.f};
    #pragma unroll
    for (int t = 0; t < 3; ++t) {
        int idx = t * 16 + c;
        float alv = (idx < CLS) ? al2[idx] : 0.f;
        float arv = (idx < CLS) ? ar2[idx] : 0.f;
        #pragma unroll
        for (int r = 0; r < 4; ++r) { pe[r] += acc[t][r] * alv; pr[r] += acc[t][r] * arv; }
    }
    #pragma unroll
    for (int mask = 1; mask <= 8; mask <<= 1) {
        #pragma unroll
        for (int r = 0; r < 4; ++r) {
            pe[r] += __shfl_xor(pe[r], mask, 64);
            pr[r] += __shfl_xor(pr[r], mask, 64);
        }
    }
    if (c == 0) {
        #pragma unroll
        for (int r = 0; r < 4; ++r) {
            int grow = rbase + r;
            if (grow < N_NODES) { el[grow] = pe[r]; er[grow] = pr[r]; }
        }
    }
}

// ---------------- fused GAT layer 1 (LDS-staged alpha/src, R9 structure) ----------------
__global__ __launch_bounds__(256) void gat1_fused(const int* __restrict__ degs,
                                                  const int* __restrict__ srcs,
                                                  const float* __restrict__ el,
                                                  const float* __restrict__ er,
                                                  const __bf16* __restrict__ feat1b,
                                                  const float* __restrict__ b1,
                                                  __bf16* __restrict__ hbufb) {
    __shared__ float a_lds[4][64 * 8];   // [wave][edge*8 + head]
    __shared__ int   s_lds[4][64];       // [wave][edge]
    int wave = threadIdx.x >> 6;
    int lane = threadIdx.x & 63;
    int d = blockIdx.x * 4 + wave;
    int off = d * STRIDE;
    int deg = degs[d];

    int h = lane & 7, slot = lane >> 3;
    int q = lane >> 4, fg = lane & 15, hd = fg >> 1;
    float er_d = er[d * 8 + h];

    f32x2 accv[4];
    #pragma unroll
    for (int j = 0; j < 4; ++j) { accv[j].x = 0.f; accv[j].y = 0.f; }

    bool fast = (deg <= 64);
    if (fast) {
        int nit = (deg + 7) >> 3;
        float sc[8];
        int sreg[8];
        float m = NEG_INF;
        #pragma unroll
        for (int it = 0; it < 8; ++it) {
            float v = NEG_INF;
            int e = it * 8 + slot;
            if (it < nit && e < deg) {
                sreg[it] = srcs[off + e];
                v = leaky(el[sreg[it] * 8 + h] + er_d);
            }
            sc[it] = v;
            m = fmaxf(m, v);
        }
        float l = 0.f;
        #pragma unroll
        for (int it = 0; it < 8; ++it)
            l += (sc[it] == NEG_INF) ? 0.f : __expf(sc[it] - m);
        #pragma unroll
        for (int mask = 8; mask <= 32; mask <<= 1) {
            float m2 = __shfl_xor(m, mask, 64);
            float l2 = __shfl_xor(l, mask, 64);
            float mn = fmaxf(m, m2);
            float f1 = (m  == NEG_INF) ? 0.f : __expf(m - mn);
            float f2 = (m2 == NEG_INF) ? 0.f : __expf(m2 - mn);
            l = l * f1 + l2 * f2;
            m = mn;
        }
        float inv_l = 1.f / (l + 1e-9f);
        #pragma unroll
        for (int it = 0; it < 8; ++it) {
            int e = it * 8 + slot;
            if (it < nit && e < deg) {
                a_lds[wave][e * 8 + h] = __expf(sc[it] - m) * inv_l;
                if (h == 0) s_lds[wave][e] = sreg[it];
            }
        }
    }
    __syncthreads();

    if (fast) {
        int ng = (deg + 3) >> 2;
        #pragma unroll 4
        for (int g = 0; g < ng; ++g) {
            int k = g * 4 + q;
            float a = 0.f;
            int se = 0;
            if (k < deg) {
                a = a_lds[wave][k * 8 + hd];
                se = s_lds[wave][k];
            }
            uint4 p = *(const uint4*)(feat1b + (size_t)se * F1 + fg * 8);
            f32x2 av; av.x = a; av.y = a;
            accv[0] += av * unpk(p.x);
            accv[1] += av * unpk(p.y);
            accv[2] += av * unpk(p.z);
            accv[3] += av * unpk(p.w);
        }
    } else {
        // slow path (deg > 64): recompute + shuffle broadcast
        float m = NEG_INF, l = 0.f;
        for (int base = 0; base < deg; base += 8) {
            int e = base + slot;
            float v = NEG_INF;
            if (e < deg) {
                int s = srcs[off + e];
                v = leaky(el[s * 8 + h] + er_d);
            }
            float mn = fmaxf(m, v);
            float f1 = (m == NEG_INF) ? 0.f : __expf(m - mn);
            float f2 = (v == NEG_INF) ? 0.f : __expf(v - mn);
            l = l * f1 + f2;
            m = mn;
        }
        #pragma unroll
        for (int mask = 8; mask <= 32; mask <<= 1) {
            float m2 = __shfl_xor(m, mask, 64);
            float l2 = __shfl_xor(l, mask, 64);
            float mn = fmaxf(m, m2);
            float f1 = (m  == NEG_INF) ? 0.f : __expf(m - mn);
            float f2 = (m2 == NEG_INF) ? 0.f : __expf(m2 - mn);
            l = l * f1 + l2 * f2;
            m = mn;
        }
        float inv_l = 1.f / (l + 1e-9f);

        for (int base = 0; base < deg; base += 8) {
            int e = base + slot;
            float alpha = 0.f;
            int s = 0;
            if (e < deg) {
                s = srcs[off + e];
                float v = leaky(el[s * 8 + h] + er_d);
                alpha = __expf(v - m) * inv_l;
            }
            #pragma unroll
            for (int sub = 0; sub < 2; ++sub) {
                int k = sub * 4 + q;
                float a  = __shfl(alpha, k * 8 + hd, 64);
                int   se = __shfl(s,     k * 8,      64);
                uint4 p = *(const uint4*)(feat1b + (size_t)se * F1 + fg * 8);
                f32x2 av; av.x = a; av.y = a;
                accv[0] += av * unpk(p.x);
                accv[1] += av * unpk(p.y);
                accv[2] += av * unpk(p.z);
                accv[3] += av * unpk(p.w);
            }
        }
    }

    float acc[8];
    #pragma unroll
    for (int j = 0; j < 4; ++j) { acc[2 * j] = accv[j].x; acc[2 * j + 1] = accv[j].y; }
    #pragma unroll
    for (int i = 0; i < 8; ++i) {
        acc[i] += __shfl_xor(acc[i], 16, 64);
        acc[i] += __shfl_xor(acc[i], 32, 64);
    }
    if (q == 0) {
        bf16x8 o;
        #pragma unroll
        for (int i = 0; i < 8; ++i) {
            float v = acc[i] + b1[fg * 8 + i];
            v = v > 0.f ? v : expm1f(v);
            o[i] = (__bf16)v;
        }
        *(bf16x8*)(hbufb + (size_t)d * F1 + fg * 8) = o;
    }
}

// ---------------- fused GAT layer 2 (LDS-staged alpha/src, R9 structure) ----------------
__global__ __launch_bounds__(256) void gat2_fused(const int* __restrict__ degs,
                                                  const int* __restrict__ srcs,
                                                  const float* __restrict__ el,
                                                  const float* __restrict__ er,
                                                  const __bf16* __restrict__ feat2p,
                                                  const float* __restrict__ b2,
                                                  float* __restrict__ out) {
    __shared__ float a_lds[4][64];
    __shared__ int   s_lds[4][64];
    int wave = threadIdx.x >> 6;
    int lane = threadIdx.x & 63;
    int d = blockIdx.x * 4 + wave;
    int off = d * STRIDE;
    int deg = degs[d];

    float er_d = er[d];
    int q  = lane >> 4;
    int cg = lane & 15;
    f32x2 accv[2];
    accv[0].x = 0.f; accv[0].y = 0.f; accv[1].x = 0.f; accv[1].y = 0.f;

    bool fast = (deg <= 64);
    if (fast) {
        float sc = NEG_INF;
        int s0 = 0;
        if (lane < deg) {
            s0 = srcs[off + lane];
            sc = leaky(el[s0] + er_d);
        }
        float m = sc, l = (sc == NEG_INF) ? 0.f : 1.f;
        #pragma unroll
        for (int mask = 1; mask <= 32; mask <<= 1) {
            float m2 = __shfl_xor(m, mask, 64);
            float l2 = __shfl_xor(l, mask, 64);
            float mn = fmaxf(m, m2);
            float f1 = (m  == NEG_INF) ? 0.f : __expf(m - mn);
            float f2 = (m2 == NEG_INF) ? 0.f : __expf(m2 - mn);
            l = l * f1 + l2 * f2;
            m = mn;
        }
        float inv_l = 1.f / (l + 1e-9f);
        if (lane < deg) {
            a_lds[wave][lane] = __expf(sc - m) * inv_l;
            s_lds[wave][lane] = s0;
        }
    }
    __syncthreads();

    if (fast) {
        int ng = (deg + 3) >> 2;
        #pragma unroll 4
        for (int g = 0; g < ng; ++g) {
            int k = g * 4 + q;
            float a = 0.f;
            int se = 0;
            if (k < deg) {
                a = a_lds[wave][k];
                se = s_lds[wave][k];
            }
            uint2 p = *(const uint2*)(feat2p + (size_t)se * CLSP + cg * 4);
            f32x2 av; av.x = a; av.y = a;
            accv[0] += av * unpk(p.x);
            accv[1] += av * unpk(p.y);
        }
    } else {
        float m = NEG_INF, l = 0.f;
        for (int base = 0; base < deg; base += 64) {
            int e = base + lane;
            float sc = NEG_INF;
            if (e < deg) {
                int s = srcs[off + e];
                sc = leaky(el[s] + er_d);
            }
            float mn = fmaxf(m, sc);
            float f1 = (m  == NEG_INF) ? 0.f : __expf(m - mn);
            float f2 = (sc == NEG_INF) ? 0.f : __expf(sc - mn);
            l = l * f1 + f2;
            m = mn;
        }
        #pragma unroll
        for (int mask = 1; mask <= 32; mask <<= 1) {
            float m2 = __shfl_xor(m, mask, 64);
            float l2 = __shfl_xor(l, mask, 64);
            float mn = fmaxf(m, m2);
            float f1 = (m  == NEG_INF) ? 0.f : __expf(m - mn);
            float f2 = (m2 == NEG_INF) ? 0.f : __expf(m2 - mn);
            l = l * f1 + l2 * f2;
            m = mn;
        }
        float inv_l = 1.f / (l + 1e-9f);

        for (int base = 0; base < deg; base += 64) {
            int e = base + lane;
            float alpha = 0.f;
            int s = 0;
            if (e < deg) {
                s = srcs[off + e];
                float sc = leaky(el[s] + er_d);
                alpha = __expf(sc - m) * inv_l;
            }
            int kmax = min(64, deg - base);
            int nsub = (kmax + 3) >> 2;
            for (int sub = 0; sub < nsub; ++sub) {
                int k = sub * 4 + q;
                float a  = __shfl(alpha, k, 64);
                int   se = __shfl(s,     k, 64);
                uint2 p = *(const uint2*)(feat2p + (size_t)se * CLSP + cg * 4);
                f32x2 av; av.x = a; av.y = a;
                accv[0] += av * unpk(p.x);
                accv[1] += av * unpk(p.y);
            }
        }
    }

    float acc[4];
    acc[0] = accv[0].x; acc[1] = accv[0].y; acc[2] = accv[1].x; acc[3] = accv[1].y;
    #pragma unroll
    for (int i = 0; i < 4; ++i) {
        acc[i] += __shfl_xor(acc[i], 16, 64);
        acc[i] += __shfl_xor(acc[i], 32, 64);
    }
    if (lane < 10) {   // q==0, cg<10
        float4 o;
        o.x = acc[0] + b2[cg * 4 + 0];
        o.y = acc[1] + b2[cg * 4 + 1];
        o.z = acc[2] + b2[cg * 4 + 2];
        o.w = acc[3] + b2[cg * 4 + 3];
        *(float4*)(out + (size_t)d * CLS + cg * 4) = o;
    }
}

// ---------------- launch ----------------
extern "C" void kernel_launch(void* const* d_in, const int* in_sizes, int n_in,
                              void* d_out, int out_size, void* d_ws, size_t ws_size,
                              hipStream_t stream) {
    const float* features = (const float*)d_in[0];
    const int*   esrc     = (const int*)d_in[1];
    const int*   edst     = (const int*)d_in[2];
    const float* W1       = (const float*)d_in[3];
    const float* al1      = (const float*)d_in[4];
    const float* ar1      = (const float*)d_in[5];
    const float* b1       = (const float*)d_in[6];
    const float* W2       = (const float*)d_in[7];
    const float* al2      = (const float*)d_in[8];
    const float* ar2      = (const float*)d_in[9];
    const float* b2       = (const float*)d_in[10];
    float* out = (float*)d_out;

    float* ws = (float*)d_ws;
    float*  el1    = ws;                        // 400,000
    float*  er1    = ws + 400000;               // 400,000
    float*  el2    = ws + 800000;               // 50,000
    float*  er2    = ws + 850000;               // 50,000
    int*    cursor = (int*)(ws + 900000);       // 50,000
    int*    srcs   = (int*)(ws + 950000);       // 4,800,000 (padded CSR)
    __bf16* feat1b = (__bf16*)(ws + 5750000);   // 6,400,000 bf16 (3.2M floats)
    __bf16* hbufb  = (__bf16*)(ws + 8950000);   // 6,400,000 bf16
    __bf16* feat2p = (__bf16*)(ws + 12150000);  // 3,200,000 bf16 (1.6M floats)
    __bf16* w1t    = (__bf16*)(ws + 13750000);  // 16,384 bf16
    __bf16* w2t    = (__bf16*)(ws + 13760000);  // 8,192 bf16
    // total ~13.77M floats = 55 MB

    const int B = 256;
    const int BPS = (N_EDGES + 255) / 256;

    setup_kernel<<<(N_NODES + B - 1) / B, B, 0, stream>>>(W1, W2, w1t, w2t, cursor);
    scatter_kernel<<<SWEEPS * BPS, B, 0, stream>>>(esrc, edst, cursor, srcs);

    gemm1_mfma<<<(N_NODES + 63) / 64, 256, 0, stream>>>(features, w1t, al1, ar1,
                                                        feat1b, el1, er1);
    gat1_fused<<<N_NODES / 4, B, 0, stream>>>(cursor, srcs, el1, er1, feat1b, b1, hbufb);

    gemm2_mfma<<<(N_NODES + 63) / 64, 256, 0, stream>>>(hbufb, w2t, al2, ar2,
                                                        feat2p, el2, er2);
    gat2_fused<<<N_NODES / 4, B, 0, stream>>>(cursor, srcs, el2, er2, feat2p, b2, out);
}

// Round 13
// 271.690 us; speedup vs baseline: 1.1632x; 1.0028x over previous
//
#include <hip/hip_runtime.h>
#include <hip/hip_bf16.h>

#define N_NODES 50000
#define N_EDGES 800000
#define IN_F    128
#define HID     16
#define HEADS   8
#define F1      128   // HEADS*HID
#define CLS     40
#define CLSP    64    // padded bf16 feat2 stride
#define NEG     0.2f
#define NEG_INF (-__builtin_inff())
#define SWEEPS      8
#define SWEEP_RANGE 6250   // N_NODES / SWEEPS; write window 2.4MB (L2-resident)
#define STRIDE      96     // padded CSR slot count per node (P(deg>96) ~ 0)

typedef __bf16 bf16x8 __attribute__((ext_vector_type(8)));
typedef float  f32x4  __attribute__((ext_vector_type(4)));
typedef float  f32x2  __attribute__((ext_vector_type(2)));

__device__ __forceinline__ float leaky(float v) { return v >= 0.0f ? v : NEG * v; }
__device__ __forceinline__ f32x2 unpk(unsigned u) {
    f32x2 r;
    r.x = __uint_as_float(u << 16);
    r.y = __uint_as_float(u & 0xffff0000u);
    return r;
}

// ---------------- setup: zero cursor + weight transposes ----------------
__global__ void setup_kernel(const float* __restrict__ W1, const float* __restrict__ W2,
                             __bf16* __restrict__ w1t, __bf16* __restrict__ w2t,
                             int* __restrict__ cursor) {
    int i = blockIdx.x * blockDim.x + threadIdx.x;
    if (i < N_NODES) cursor[i] = 0;
    if (i < 128 * 128) {
        int n = i >> 7, k = i & 127;
        w1t[i] = (__bf16)W1[k * 128 + n];
    }
    if (i < CLSP * 128) {
        int n = i >> 7, k = i & 127;
        w2t[i] = (n < CLS) ? (__bf16)W2[k * CLS + n] : (__bf16)0.0f;
    }
}

// ---------------- swept scatter into padded CSR ----------------
__global__ void scatter_kernel(const int* __restrict__ src, const int* __restrict__ dst,
                               int* __restrict__ cursor, int* __restrict__ srcs_sorted) {
    const int BPS = (N_EDGES + 255) / 256;
    int sweep = blockIdx.x / BPS;
    int e = (blockIdx.x - sweep * BPS) * 256 + threadIdx.x;
    if (e >= N_EDGES) return;
    int d = dst[e];
    int lo = sweep * SWEEP_RANGE;
    if (d < lo || d >= lo + SWEEP_RANGE) return;
    int pos = d * STRIDE + atomicAdd(&cursor[d], 1);
    srcs_sorted[pos] = src[e];
}

// ---------------- GEMM1 + fused elr1 epilogue ----------------
__global__ __launch_bounds__(256) void gemm1_mfma(const float* __restrict__ A,
                                                  const __bf16* __restrict__ Wt,
                                                  const float* __restrict__ al1,
                                                  const float* __restrict__ ar1,
                                                  __bf16* __restrict__ outb,
                                                  float* __restrict__ el,
                                                  float* __restrict__ er) {
    int wave = threadIdx.x >> 6, lane = threadIdx.x & 63;
    int m0 = blockIdx.x * 64 + wave * 16;
    int c = lane & 15;
    int row = m0 + c;
    int rowc = row < N_NODES ? row : N_NODES - 1;
    int ko = (lane >> 4) * 8;

    f32x4 acc[8];
    #pragma unroll
    for (int t = 0; t < 8; ++t)
        #pragma unroll
        for (int r = 0; r < 4; ++r) acc[t][r] = 0.f;

    for (int ks = 0; ks < 128; ks += 32) {
        const float* ap = A + (size_t)rowc * 128 + ks + ko;
        float4 u = *(const float4*)ap;
        float4 v = *(const float4*)(ap + 4);
        bf16x8 a;
        a[0] = (__bf16)u.x; a[1] = (__bf16)u.y; a[2] = (__bf16)u.z; a[3] = (__bf16)u.w;
        a[4] = (__bf16)v.x; a[5] = (__bf16)v.y; a[6] = (__bf16)v.z; a[7] = (__bf16)v.w;
        #pragma unroll
        for (int t = 0; t < 8; ++t) {
            bf16x8 b = *(const bf16x8*)(Wt + (size_t)(t * 16 + c) * 128 + ks + ko);
            acc[t] = __builtin_amdgcn_mfma_f32_16x16x32_bf16(a, b, acc[t], 0, 0, 0);
        }
    }
    int rbase = m0 + (lane >> 4) * 4;
    #pragma unroll
    for (int t = 0; t < 8; ++t) {
        int gcol = t * 16 + c;
        #pragma unroll
        for (int r = 0; r < 4; ++r) {
            int grow = rbase + r;
            if (grow < N_NODES) outb[(size_t)grow * 128 + gcol] = (__bf16)acc[t][r];
        }
    }
    // fused elr1
    #pragma unroll
    for (int t = 0; t < 8; ++t) {
        float alv = al1[t * 16 + c];
        float arv = ar1[t * 16 + c];
        float pe[4], pr[4];
        #pragma unroll
        for (int r = 0; r < 4; ++r) { pe[r] = acc[t][r] * alv; pr[r] = acc[t][r] * arv; }
        #pragma unroll
        for (int mask = 1; mask <= 8; mask <<= 1) {
            #pragma unroll
            for (int r = 0; r < 4; ++r) {
                pe[r] += __shfl_xor(pe[r], mask, 64);
                pr[r] += __shfl_xor(pr[r], mask, 64);
            }
        }
        if (c == 0) {
            #pragma unroll
            for (int r = 0; r < 4; ++r) {
                int grow = rbase + r;
                if (grow < N_NODES) {
                    el[grow * 8 + t] = pe[r];
                    er[grow * 8 + t] = pr[r];
                }
            }
        }
    }
}

// ---------------- GEMM2 + fused elr2 epilogue ----------------
__global__ __launch_bounds__(256) void gemm2_mfma(const __bf16* __restrict__ A,
                                                  const __bf16* __restrict__ Wt,
                                                  const float* __restrict__ al2,
                                                  const float* __restrict__ ar2,
                                                  __bf16* __restrict__ out,
                                                  float* __restrict__ el,
                                                  float* __restrict__ er) {
    int wave = threadIdx.x >> 6, lane = threadIdx.x & 63;
    int m0 = blockIdx.x * 64 + wave * 16;
    int c = lane & 15;
    int row = m0 + c;
    int rowc = row < N_NODES ? row : N_NODES - 1;
    int ko = (lane >> 4) * 8;

    f32x4 acc[4];
    #pragma unroll
    for (int t = 0; t < 4; ++t)
        #pragma unroll
        for (int r = 0; r < 4; ++r) acc[t][r] = 0.f;

    for (int ks = 0; ks < 128; ks += 32) {
        bf16x8 a = *(const bf16x8*)(A + (size_t)rowc * 128 + ks + ko);
        #pragma unroll
        for (int t = 0; t < 4; ++t) {
            bf16x8 b = *(const bf16x8*)(Wt + (size_t)(t * 16 + c) * 128 + ks + ko);
            acc[t] = __builtin_amdgcn_mfma_f32_16x16x32_bf16(a, b, acc[t], 0, 0, 0);
        }
    }
    int rbase = m0 + (lane >> 4) * 4;
    #pragma unroll
    for (int t = 0; t < 4; ++t) {
        int gcol = t * 16 + c;
        #pragma unroll
        for (int r = 0; r < 4; ++r) {
            int grow = rbase + r;
            if (grow < N_NODES) out[(size_t)grow * CLSP + gcol] = (__bf16)acc[t][r];
        }
    }
    float pe[4] = {0.f, 0.f, 0.f, 0.f}, pr[4] = {0.f, 0.f, 0.f, 0.f};
    #pragma unroll
    for (int t = 0; t < 3; ++t) {
        int idx = t * 16 + c;
        float alv = (idx < CLS) ? al2[idx] : 0.f;
        float arv = (idx < CLS) ? ar2[idx] : 0.f;
        #pragma unroll
        for (int r = 0; r < 4; ++r) { pe[r] += acc[t][r] * alv; pr[r] += acc[t][r] * arv; }
    }
    #pragma unroll
    for (int mask = 1; mask <= 8; mask <<= 1) {
        #pragma unroll
        for (int r = 0; r < 4; ++r) {
            pe[r] += __shfl_xor(pe[r], mask, 64);
            pr[r] += __shfl_xor(pr[r], mask, 64);
        }
    }
    if (c == 0) {
        #pragma unroll
        for (int r = 0; r < 4; ++r) {
            int grow = rbase + r;
            if (grow < N_NODES) { el[grow] = pe[r]; er[grow] = pr[r]; }
        }
    }
}

// ---------------- fused GAT layer 1 (LDS-staged alpha/src) ----------------
__global__ __launch_bounds__(256) void gat1_fused(const int* __restrict__ degs,
                                                  const int* __restrict__ srcs,
                                                  const float* __restrict__ el,
                                                  const float* __restrict__ er,
                                                  const __bf16* __restrict__ feat1b,
                                                  const float* __restrict__ b1,
                                                  __bf16* __restrict__ hbufb) {
    __shared__ float a_lds[4][64 * 8];   // [wave][edge*8 + head]
    __shared__ int   s_lds[4][64];       // [wave][edge]
    int wave = threadIdx.x >> 6;
    int lane = threadIdx.x & 63;
    int d = blockIdx.x * 4 + wave;
    int off = d * STRIDE;
    int deg = degs[d];

    int h = lane & 7, slot = lane >> 3;
    int q = lane >> 4, fg = lane & 15, hd = fg >> 1;
    float er_d = er[d * 8 + h];

    f32x2 accv[4];
    #pragma unroll
    for (int j = 0; j < 4; ++j) { accv[j].x = 0.f; accv[j].y = 0.f; }

    bool fast = (deg <= 64);
    if (fast) {
        int nit = (deg + 7) >> 3;
        float sc[8];
        int sreg[8];
        float m = NEG_INF;
        #pragma unroll
        for (int it = 0; it < 8; ++it) {
            float v = NEG_INF;
            int e = it * 8 + slot;
            if (it < nit && e < deg) {
                sreg[it] = srcs[off + e];
                v = leaky(el[sreg[it] * 8 + h] + er_d);
            }
            sc[it] = v;
            m = fmaxf(m, v);
        }
        float l = 0.f;
        #pragma unroll
        for (int it = 0; it < 8; ++it)
            l += (sc[it] == NEG_INF) ? 0.f : __expf(sc[it] - m);
        #pragma unroll
        for (int mask = 8; mask <= 32; mask <<= 1) {
            float m2 = __shfl_xor(m, mask, 64);
            float l2 = __shfl_xor(l, mask, 64);
            float mn = fmaxf(m, m2);
            float f1 = (m  == NEG_INF) ? 0.f : __expf(m - mn);
            float f2 = (m2 == NEG_INF) ? 0.f : __expf(m2 - mn);
            l = l * f1 + l2 * f2;
            m = mn;
        }
        float inv_l = 1.f / (l + 1e-9f);
        #pragma unroll
        for (int it = 0; it < 8; ++it) {
            int e = it * 8 + slot;
            if (it < nit && e < deg) {
                a_lds[wave][e * 8 + h] = __expf(sc[it] - m) * inv_l;
                if (h == 0) s_lds[wave][e] = sreg[it];
            }
        }
    }
    __syncthreads();

    if (fast) {
        int ng = (deg + 3) >> 2;
        #pragma unroll 4
        for (int g = 0; g < ng; ++g) {
            int k = g * 4 + q;
            float a = 0.f;
            int se = 0;
            if (k < deg) {
                a = a_lds[wave][k * 8 + hd];
                se = s_lds[wave][k];
            }
            uint4 p = *(const uint4*)(feat1b + (size_t)se * F1 + fg * 8);
            f32x2 av; av.x = a; av.y = a;
            accv[0] += av * unpk(p.x);
            accv[1] += av * unpk(p.y);
            accv[2] += av * unpk(p.z);
            accv[3] += av * unpk(p.w);
        }
    } else {
        // slow path (deg > 64): recompute + shuffle broadcast
        float m = NEG_INF, l = 0.f;
        for (int base = 0; base < deg; base += 8) {
            int e = base + slot;
            float v = NEG_INF;
            if (e < deg) {
                int s = srcs[off + e];
                v = leaky(el[s * 8 + h] + er_d);
            }
            float mn = fmaxf(m, v);
            float f1 = (m == NEG_INF) ? 0.f : __expf(m - mn);
            float f2 = (v == NEG_INF) ? 0.f : __expf(v - mn);
            l = l * f1 + f2;
            m = mn;
        }
        #pragma unroll
        for (int mask = 8; mask <= 32; mask <<= 1) {
            float m2 = __shfl_xor(m, mask, 64);
            float l2 = __shfl_xor(l, mask, 64);
            float mn = fmaxf(m, m2);
            float f1 = (m  == NEG_INF) ? 0.f : __expf(m - mn);
            float f2 = (m2 == NEG_INF) ? 0.f : __expf(m2 - mn);
            l = l * f1 + l2 * f2;
            m = mn;
        }
        float inv_l = 1.f / (l + 1e-9f);

        for (int base = 0; base < deg; base += 8) {
            int e = base + slot;
            float alpha = 0.f;
            int s = 0;
            if (e < deg) {
                s = srcs[off + e];
                float v = leaky(el[s * 8 + h] + er_d);
                alpha = __expf(v - m) * inv_l;
            }
            #pragma unroll
            for (int sub = 0; sub < 2; ++sub) {
                int k = sub * 4 + q;
                float a  = __shfl(alpha, k * 8 + hd, 64);
                int   se = __shfl(s,     k * 8,      64);
                uint4 p = *(const uint4*)(feat1b + (size_t)se * F1 + fg * 8);
                f32x2 av; av.x = a; av.y = a;
                accv[0] += av * unpk(p.x);
                accv[1] += av * unpk(p.y);
                accv[2] += av * unpk(p.z);
                accv[3] += av * unpk(p.w);
            }
        }
    }

    float acc[8];
    #pragma unroll
    for (int j = 0; j < 4; ++j) { acc[2 * j] = accv[j].x; acc[2 * j + 1] = accv[j].y; }
    #pragma unroll
    for (int i = 0; i < 8; ++i) {
        acc[i] += __shfl_xor(acc[i], 16, 64);
        acc[i] += __shfl_xor(acc[i], 32, 64);
    }
    if (q == 0) {
        bf16x8 o;
        #pragma unroll
        for (int i = 0; i < 8; ++i) {
            float v = acc[i] + b1[fg * 8 + i];
            v = v > 0.f ? v : expm1f(v);
            o[i] = (__bf16)v;
        }
        *(bf16x8*)(hbufb + (size_t)d * F1 + fg * 8) = o;
    }
}

// ---------------- fused GAT layer 2 (8-edge groups, 16B loads) ----------------
// Fast path: q2=lane>>3 (edge subslot, 8 edges/iter), cg8=lane&7 covers cols
// cg8*8..cg8*8+7 (16B uint4 loads of bf16 feat2p, stride 64).
__global__ __launch_bounds__(256) void gat2_fused(const int* __restrict__ degs,
                                                  const int* __restrict__ srcs,
                                                  const float* __restrict__ el,
                                                  const float* __restrict__ er,
                                                  const __bf16* __restrict__ feat2p,
                                                  const float* __restrict__ b2,
                                                  float* __restrict__ out) {
    __shared__ float a_lds[4][64];
    __shared__ int   s_lds[4][64];
    int wave = threadIdx.x >> 6;
    int lane = threadIdx.x & 63;
    int d = blockIdx.x * 4 + wave;
    int off = d * STRIDE;
    int deg = degs[d];

    float er_d = er[d];
    bool fast = (deg <= 64);
    if (fast) {
        float sc = NEG_INF;
        int s0 = 0;
        if (lane < deg) {
            s0 = srcs[off + lane];
            sc = leaky(el[s0] + er_d);
        }
        float m = sc, l = (sc == NEG_INF) ? 0.f : 1.f;
        #pragma unroll
        for (int mask = 1; mask <= 32; mask <<= 1) {
            float m2 = __shfl_xor(m, mask, 64);
            float l2 = __shfl_xor(l, mask, 64);
            float mn = fmaxf(m, m2);
            float f1 = (m  == NEG_INF) ? 0.f : __expf(m - mn);
            float f2 = (m2 == NEG_INF) ? 0.f : __expf(m2 - mn);
            l = l * f1 + l2 * f2;
            m = mn;
        }
        float inv_l = 1.f / (l + 1e-9f);
        if (lane < deg) {
            a_lds[wave][lane] = __expf(sc - m) * inv_l;
            s_lds[wave][lane] = s0;
        }
    }
    __syncthreads();

    if (fast) {
        int q2  = lane >> 3;
        int cg8 = lane & 7;
        f32x2 accv[4];
        #pragma unroll
        for (int j = 0; j < 4; ++j) { accv[j].x = 0.f; accv[j].y = 0.f; }

        int ng = (deg + 7) >> 3;
        #pragma unroll 4
        for (int g = 0; g < ng; ++g) {
            int k = g * 8 + q2;
            float a = 0.f;
            int se = 0;
            if (k < deg) {
                a = a_lds[wave][k];
                se = s_lds[wave][k];
            }
            uint4 p = *(const uint4*)(feat2p + (size_t)se * CLSP + cg8 * 8);
            f32x2 av; av.x = a; av.y = a;
            accv[0] += av * unpk(p.x);
            accv[1] += av * unpk(p.y);
            accv[2] += av * unpk(p.z);
            accv[3] += av * unpk(p.w);
        }
        float acc[8];
        #pragma unroll
        for (int j = 0; j < 4; ++j) { acc[2 * j] = accv[j].x; acc[2 * j + 1] = accv[j].y; }
        #pragma unroll
        for (int i = 0; i < 8; ++i) {
            acc[i] += __shfl_xor(acc[i], 8, 64);
            acc[i] += __shfl_xor(acc[i], 16, 64);
            acc[i] += __shfl_xor(acc[i], 32, 64);
        }
        if (q2 == 0 && cg8 < 5) {   // cols cg8*8..cg8*8+7 (all < 40)
            float4 o0, o1;
            o0.x = acc[0] + b2[cg8 * 8 + 0];
            o0.y = acc[1] + b2[cg8 * 8 + 1];
            o0.z = acc[2] + b2[cg8 * 8 + 2];
            o0.w = acc[3] + b2[cg8 * 8 + 3];
            o1.x = acc[4] + b2[cg8 * 8 + 4];
            o1.y = acc[5] + b2[cg8 * 8 + 5];
            o1.z = acc[6] + b2[cg8 * 8 + 6];
            o1.w = acc[7] + b2[cg8 * 8 + 7];
            *(float4*)(out + (size_t)d * CLS + cg8 * 8)     = o0;
            *(float4*)(out + (size_t)d * CLS + cg8 * 8 + 4) = o1;
        }
    } else {
        // slow path (deg > 64): 4-edge groups, uint2 loads, old layout
        int q  = lane >> 4;
        int cg = lane & 15;
        f32x2 accv[2];
        accv[0].x = 0.f; accv[0].y = 0.f; accv[1].x = 0.f; accv[1].y = 0.f;

        float m = NEG_INF, l = 0.f;
        for (int base = 0; base < deg; base += 64) {
            int e = base + lane;
            float sc = NEG_INF;
            if (e < deg) {
                int s = srcs[off + e];
                sc = leaky(el[s] + er_d);
            }
            float mn = fmaxf(m, sc);
            float f1 = (m  == NEG_INF) ? 0.f : __expf(m - mn);
            float f2 = (sc == NEG_INF) ? 0.f : __expf(sc - mn);
            l = l * f1 + f2;
            m = mn;
        }
        #pragma unroll
        for (int mask = 1; mask <= 32; mask <<= 1) {
            float m2 = __shfl_xor(m, mask, 64);
            float l2 = __shfl_xor(l, mask, 64);
            float mn = fmaxf(m, m2);
            float f1 = (m  == NEG_INF) ? 0.f : __expf(m - mn);
            float f2 = (m2 == NEG_INF) ? 0.f : __expf(m2 - mn);
            l = l * f1 + l2 * f2;
            m = mn;
        }
        float inv_l = 1.f / (l + 1e-9f);

        for (int base = 0; base < deg; base += 64) {
            int e = base + lane;
            float alpha = 0.f;
            int s = 0;
            if (e < deg) {
                s = srcs[off + e];
                float sc = leaky(el[s] + er_d);
                alpha = __expf(sc - m) * inv_l;
            }
            int kmax = min(64, deg - base);
            int nsub = (kmax + 3) >> 2;
            for (int sub = 0; sub < nsub; ++sub) {
                int k = sub * 4 + q;
                float a  = __shfl(alpha, k, 64);
                int   se = __shfl(s,     k, 64);
                uint2 p = *(const uint2*)(feat2p + (size_t)se * CLSP + cg * 4);
                f32x2 av; av.x = a; av.y = a;
                accv[0] += av * unpk(p.x);
                accv[1] += av * unpk(p.y);
            }
        }
        float acc[4];
        acc[0] = accv[0].x; acc[1] = accv[0].y; acc[2] = accv[1].x; acc[3] = accv[1].y;
        #pragma unroll
        for (int i = 0; i < 4; ++i) {
            acc[i] += __shfl_xor(acc[i], 16, 64);
            acc[i] += __shfl_xor(acc[i], 32, 64);
        }
        if (lane < 10) {   // q==0, cg<10
            float4 o;
            o.x = acc[0] + b2[cg * 4 + 0];
            o.y = acc[1] + b2[cg * 4 + 1];
            o.z = acc[2] + b2[cg * 4 + 2];
            o.w = acc[3] + b2[cg * 4 + 3];
            *(float4*)(out + (size_t)d * CLS + cg * 4) = o;
        }
    }
}

// ---------------- launch ----------------
extern "C" void kernel_launch(void* const* d_in, const int* in_sizes, int n_in,
                              void* d_out, int out_size, void* d_ws, size_t ws_size,
                              hipStream_t stream) {
    const float* features = (const float*)d_in[0];
    const int*   esrc     = (const int*)d_in[1];
    const int*   edst     = (const int*)d_in[2];
    const float* W1       = (const float*)d_in[3];
    const float* al1      = (const float*)d_in[4];
    const float* ar1      = (const float*)d_in[5];
    const float* b1       = (const float*)d_in[6];
    const float* W2       = (const float*)d_in[7];
    const float* al2      = (const float*)d_in[8];
    const float* ar2      = (const float*)d_in[9];
    const float* b2       = (const float*)d_in[10];
    float* out = (float*)d_out;

    float* ws = (float*)d_ws;
    float*  el1    = ws;                        // 400,000
    float*  er1    = ws + 400000;               // 400,000
    float*  el2    = ws + 800000;               // 50,000
    float*  er2    = ws + 850000;               // 50,000
    int*    cursor = (int*)(ws + 900000);       // 50,000
    int*    srcs   = (int*)(ws + 950000);       // 4,800,000 (padded CSR)
    __bf16* feat1b = (__bf16*)(ws + 5750000);   // 6,400,000 bf16 (3.2M floats)
    __bf16* hbufb  = (__bf16*)(ws + 8950000);   // 6,400,000 bf16
    __bf16* feat2p = (__bf16*)(ws + 12150000);  // 3,200,000 bf16 (1.6M floats)
    __bf16* w1t    = (__bf16*)(ws + 13750000);  // 16,384 bf16
    __bf16* w2t    = (__bf16*)(ws + 13760000);  // 8,192 bf16
    // total ~13.77M floats = 55 MB

    const int B = 256;
    const int BPS = (N_EDGES + 255) / 256;

    setup_kernel<<<(N_NODES + B - 1) / B, B, 0, stream>>>(W1, W2, w1t, w2t, cursor);
    scatter_kernel<<<SWEEPS * BPS, B, 0, stream>>>(esrc, edst, cursor, srcs);

    gemm1_mfma<<<(N_NODES + 63) / 64, 256, 0, stream>>>(features, w1t, al1, ar1,
                                                        feat1b, el1, er1);
    gat1_fused<<<N_NODES / 4, B, 0, stream>>>(cursor, srcs, el1, er1, feat1b, b1, hbufb);

    gemm2_mfma<<<(N_NODES + 63) / 64, 256, 0, stream>>>(hbufb, w2t, al2, ar2,
                                                        feat2p, el2, er2);
    gat2_fused<<<N_NODES / 4, B, 0, stream>>>(cursor, srcs, el2, er2, feat2p, b2, out);
}